// Round 1
// baseline (340.589 us; speedup 1.0000x reference)
//
#include <hip/hip_runtime.h>
#include <hip/hip_bf16.h>
#include <cstdint>

#define B_   2
#define N_   1024
#define DN_  128
#define DE_  16
#define DG_  128
#define MID_ 64
#define OUT_ 128
#define TI_  4
#define PR_ROWS 4

typedef short bf16x8 __attribute__((ext_vector_type(8)));
typedef float f32x4  __attribute__((ext_vector_type(4)));

__device__ inline short f2bf(float f) {
    union { float f; unsigned u; } v; v.f = f;
    unsigned r = v.u + 0x7FFFu + ((v.u >> 16) & 1u);   // RTNE
    return (short)(unsigned short)(r >> 16);
}

__device__ inline unsigned pk2(float lo, float hi) {
    union { __hip_bfloat162 h; unsigned u; } p;
    p.h = __float22bfloat162_rn(make_float2(lo, hi));  // v_cvt_pk_bf16_f32
    return p.u;
}

// ---------------------------------------------------------------------------
// Fused prep kernel (unchanged — ~25us, not the bottleneck).
//  blocks 0..511 : per-node projections, 4 rows/block.
//  block 512     : We -> MFMA B-fragment layout (bf16, K 16->32 zero-pad)
//  block 513     : pg[b] = g@Wg + bg
// ---------------------------------------------------------------------------
__global__ void __launch_bounds__(384) prep_all(
    const float* __restrict__ features, const float* __restrict__ g_features,
    const float* __restrict__ Wm, const float* __restrict__ bm,
    const float* __restrict__ Wskip, const float* __restrict__ bskip,
    const float* __restrict__ W1, const float* __restrict__ b1,
    const float* __restrict__ W2, const float* __restrict__ b2,
    const float* __restrict__ We, const float* __restrict__ be,
    const float* __restrict__ Wg, const float* __restrict__ bg,
    float* __restrict__ values, float* __restrict__ skipo,
    float* __restrict__ P1x, float* __restrict__ p2,
    float* __restrict__ pg, short* __restrict__ We_frag)
{
    const int t   = threadIdx.x;
    const int blk = blockIdx.x;

    if (blk == 512) {                       // --- We fragment prep ---
        for (int e = t; e < 4 * 64 * 8; e += 384) {
            const int c    = e >> 9;
            const int lane = (e >> 3) & 63;
            const int j    = e & 7;
            const int quad = lane >> 4, s = lane & 15;
            short v = 0;
            if (quad < 2) v = f2bf(We[(quad * 8 + j) * MID_ + c * 16 + s]);
            We_frag[e] = v;
        }
        return;
    }
    if (blk == 513) {                       // --- pg ---
        if (t < MID_) {
            float a0 = bg[t], a1 = bg[t];
            for (int k = 0; k < DG_; ++k) {
                const float w = Wg[k * MID_ + t];
                a0 += g_features[k] * w;
                a1 += g_features[DG_ + k] * w;
            }
            pg[t] = a0; pg[MID_ + t] = a1;
        }
        return;
    }

    // --- per-node projections ---
    const int r0 = blk * PR_ROWS;
    __shared__ float feat[PR_ROWS][DN_];
    for (int idx = t; idx < PR_ROWS * DN_; idx += 384)
        feat[idx >> 7][idx & 127] = features[(size_t)r0 * DN_ + idx];
    __syncthreads();

    const float* W; int c, stride; float base; float* outp; int ostride;
    if (t < 128) {
        W = Wm;    c = t;       stride = OUT_; base = bm[c];
        outp = values + (size_t)r0 * OUT_ + c; ostride = OUT_;
    } else if (t < 256) {
        W = Wskip; c = t - 128; stride = OUT_; base = bskip[c];
        outp = skipo + (size_t)r0 * OUT_ + c;  ostride = OUT_;
    } else if (t < 320) {
        W = W1;    c = t - 256; stride = MID_; base = b1[c] + be[c];
        outp = P1x + (size_t)r0 * MID_ + c;    ostride = MID_;
    } else {
        W = W2;    c = t - 320; stride = MID_; base = b2[c];
        outp = p2 + (size_t)r0 * MID_ + c;     ostride = MID_;
    }

    float acc[PR_ROWS] = {};
    for (int k = 0; k < DN_; ++k) {
        const float w = W[k * stride + c];
        #pragma unroll
        for (int q = 0; q < PR_ROWS; ++q) acc[q] += feat[q][k] * w;
    }
    #pragma unroll
    for (int q = 0; q < PR_ROWS; ++q) outp[q * ostride] = acc[q] + base;
}

// ---------------------------------------------------------------------------
// Main fused kernel: 512 blocks x 512 threads (8 waves), TI=4 i-rows/block.
// Occupancy was the bottleneck (grid-capped at 8 waves/CU = 25%); 8 waves/block
// at unchanged per-thread code keeps 2 blocks/CU resident -> 16 waves/CU (50%),
// the VGPR(~100)-imposed cap. Work split:
//   Pass A: wave wv owns tiles {wv + 8*it}, it=0..7 (was wv + 4*it, it=0..15).
//   Pass B: wave wv does row (wv&3), half (wv>>2); LDS combine of max/sum.
//   Pass C: 8 waves x 4 j-lanes x 32 k-steps; redv has 8 planes.
// ---------------------------------------------------------------------------
__global__ void __launch_bounds__(512, 4) gat_main(
    const float* __restrict__ e_features, const float* __restrict__ adj,
    const short* __restrict__ We_frag, const float* __restrict__ Wa,
    const float* __restrict__ values, const float* __restrict__ skipo,
    const float* __restrict__ P1x, const float* __restrict__ p2,
    const float* __restrict__ pg, float* __restrict__ out)
{
    const int t    = threadIdx.x;
    const int wv   = t >> 6;                          // 0..7
    const int l    = t & 63;
    const int quad = l >> 4;
    const int s    = l & 15;
    const int r    = blockIdx.x;
    const int b    = (r >> 2) & 1;                    // XCD r%8 -> one batch
    const int i0   = (((r >> 3) << 2) | (r & 3)) * TI_;

    __shared__ float lgP[TI_][N_];
    __shared__ float redv[8][16][36];
    __shared__ float sinv[TI_];
    __shared__ float pmax[8];
    __shared__ float psum[8];

    // ---- block constants ----
    bf16x8 bfr[4];
    float  wa_r[4], p2i[TI_][4];
    #pragma unroll
    for (int c = 0; c < 4; ++c) {
        bfr[c]  = *(const bf16x8*)&We_frag[(c * 64 + l) * 8];
        wa_r[c] = Wa[c * 16 + s];
        const float pgc = pg[b * MID_ + c * 16 + s];
        #pragma unroll
        for (int ii = 0; ii < TI_; ++ii)
            p2i[ii][c] = p2[((size_t)(b * N_ + i0 + ii)) * MID_ + c * 16 + s] + pgc;
    }
    const size_t erow0 = (size_t)(b * N_ + i0) * N_;  // in e rows

    // ---- Pass A: software-pipelined logits (8 waves x 8 tiles) ----
    float4 eA[TI_][2];
    if (quad < 2) {
        #pragma unroll
        for (int ii = 0; ii < TI_; ++ii) {
            const float* ep = &e_features[(erow0 + (size_t)ii * N_ + wv * 16 + s) * DE_ + quad * 8];
            eA[ii][0] = *(const float4*)ep;
            eA[ii][1] = *(const float4*)(ep + 4);
        }
    }
    for (int it = 0; it < 8; ++it) {
        const int tile = wv + it * 8;
        const int j0   = tile * 16;

        // pack current tile's e into bf16 A-fragments
        unsigned af[TI_][4];
        #pragma unroll
        for (int ii = 0; ii < TI_; ++ii) {
            if (quad < 2) {
                af[ii][0] = pk2(eA[ii][0].x, eA[ii][0].y);
                af[ii][1] = pk2(eA[ii][0].z, eA[ii][0].w);
                af[ii][2] = pk2(eA[ii][1].x, eA[ii][1].y);
                af[ii][3] = pk2(eA[ii][1].z, eA[ii][1].w);
            } else {
                af[ii][0] = af[ii][1] = af[ii][2] = af[ii][3] = 0u;
            }
        }
        // prefetch next tile (fire-and-forget; consumed next iteration)
        if (it < 7) {
            const int jn = (tile + 8) * 16;
            if (quad < 2) {
                #pragma unroll
                for (int ii = 0; ii < TI_; ++ii) {
                    const float* ep = &e_features[(erow0 + (size_t)ii * N_ + jn + s) * DE_ + quad * 8];
                    eA[ii][0] = *(const float4*)ep;
                    eA[ii][1] = *(const float4*)(ep + 4);
                }
            }
        }
        // P1x bias tile (off MFMA critical path — consumed in epilogue)
        float base[4][4];
        {
            const float* pb = &P1x[((size_t)(b * N_) + j0 + quad * 4) * MID_ + s];
            #pragma unroll
            for (int c = 0; c < 4; ++c)
                #pragma unroll
                for (int rr = 0; rr < 4; ++rr)
                    base[c][rr] = pb[rr * MID_ + c * 16];
        }
        #pragma unroll
        for (int ii = 0; ii < TI_; ++ii) {
            union { unsigned u[4]; bf16x8 v; } a;
            a.u[0] = af[ii][0]; a.u[1] = af[ii][1];
            a.u[2] = af[ii][2]; a.u[3] = af[ii][3];
            f32x4 acc[4];
            #pragma unroll
            for (int c = 0; c < 4; ++c) {
                acc[c] = (f32x4){0.f, 0.f, 0.f, 0.f};
                acc[c] = __builtin_amdgcn_mfma_f32_16x16x32_bf16(a.v, bfr[c], acc[c], 0, 0, 0);
            }
            float tt[4];
            #pragma unroll
            for (int rr = 0; rr < 4; ++rr) {
                float x0 = acc[0][rr] + base[0][rr] + p2i[ii][0];
                float x1 = acc[1][rr] + base[1][rr] + p2i[ii][1];
                float x2 = acc[2][rr] + base[2][rr] + p2i[ii][2];
                float x3 = acc[3][rr] + base[3][rr] + p2i[ii][3];
                x0 = fmaxf(x0, 0.01f * x0);
                x1 = fmaxf(x1, 0.01f * x1);
                x2 = fmaxf(x2, 0.01f * x2);
                x3 = fmaxf(x3, 0.01f * x3);
                tt[rr] = x0 * wa_r[0] + x1 * wa_r[1] + x2 * wa_r[2] + x3 * wa_r[3];
            }
            #pragma unroll
            for (int o = 1; o < 16; o <<= 1) {
                tt[0] += __shfl_xor(tt[0], o);
                tt[1] += __shfl_xor(tt[1], o);
                tt[2] += __shfl_xor(tt[2], o);
                tt[3] += __shfl_xor(tt[3], o);
            }
            if (s < 4) lgP[ii][j0 + quad * 4 + s] = tt[s];
        }
    }
    __syncthreads();

    // ---- Pass B: masked softmax, wave wv owns row (wv&3), half (wv>>2) ----
    {
        const int rw = wv & 3, h = wv >> 2;
        const int c0 = h * 512 + l * 4;
        const size_t arb = (size_t)(b * N_ + i0 + rw) * N_;
        float4 lv[2], av[2];
        #pragma unroll
        for (int q = 0; q < 2; ++q) {
            lv[q] = *(const float4*)&lgP[rw][c0 + 256 * q];
            av[q] = *(const float4*)&adj[arb + c0 + 256 * q];
        }
        const float NEG = -3.4e38f;
        float m = NEG;
        #pragma unroll
        for (int q = 0; q < 2; ++q) {
            m = fmaxf(m, av[q].x > 0.f ? lv[q].x : NEG);
            m = fmaxf(m, av[q].y > 0.f ? lv[q].y : NEG);
            m = fmaxf(m, av[q].z > 0.f ? lv[q].z : NEG);
            m = fmaxf(m, av[q].w > 0.f ? lv[q].w : NEG);
        }
        #pragma unroll
        for (int o = 1; o < 64; o <<= 1) m = fmaxf(m, __shfl_xor(m, o));
        if (l == 0) pmax[wv] = m;
        __syncthreads();
        m = fmaxf(pmax[rw], pmax[4 + rw]);
        float sum = 0.f;
        #pragma unroll
        for (int q = 0; q < 2; ++q) {
            float4 e4;
            e4.x = av[q].x > 0.f ? __expf(lv[q].x - m) : 0.f;
            e4.y = av[q].y > 0.f ? __expf(lv[q].y - m) : 0.f;
            e4.z = av[q].z > 0.f ? __expf(lv[q].z - m) : 0.f;
            e4.w = av[q].w > 0.f ? __expf(lv[q].w - m) : 0.f;
            *(float4*)&lgP[rw][c0 + 256 * q] = e4;
            sum += (e4.x + e4.y) + (e4.z + e4.w);
        }
        #pragma unroll
        for (int o = 1; o < 64; o <<= 1) sum += __shfl_xor(sum, o);
        if (l == 0) psum[wv] = sum;
        __syncthreads();
        if (t < TI_) sinv[t] = 1.0f / (psum[t] + psum[t + 4]);
        // no extra barrier: lgP exp-writes are pre-psum-barrier; sinv is read
        // only after the redv barrier below.
    }

    // ---- Pass C: (exp @ values) shared across the 4 i-rows ----
    const int cg = l & 15, jp = l >> 4, ch0 = cg * 8;
    float acc[TI_][8] = {};
    const float* vb = values + (size_t)b * N_ * OUT_ + ch0;
    for (int k = 0; k < 32; ++k) {
        const int j = wv * 4 + jp + k * 32;
        float cw[TI_];
        #pragma unroll
        for (int ii = 0; ii < TI_; ++ii) cw[ii] = lgP[ii][j];
        const float* vp = vb + (size_t)j * OUT_;
        const float4 v0 = *(const float4*)vp;
        const float4 v1 = *(const float4*)(vp + 4);
        const float vv[8] = {v0.x, v0.y, v0.z, v0.w, v1.x, v1.y, v1.z, v1.w};
        #pragma unroll
        for (int ii = 0; ii < TI_; ++ii)
            #pragma unroll
            for (int kk = 0; kk < 8; ++kk)
                acc[ii][kk] += cw[ii] * vv[kk];
    }
    #pragma unroll
    for (int ii = 0; ii < TI_; ++ii)
        #pragma unroll
        for (int kk = 0; kk < 8; ++kk) {
            acc[ii][kk] += __shfl_xor(acc[ii][kk], 16);
            acc[ii][kk] += __shfl_xor(acc[ii][kk], 32);
        }
    if (l < 16) {
        #pragma unroll
        for (int ii = 0; ii < TI_; ++ii)
            #pragma unroll
            for (int q = 0; q < 2; ++q) {
                float4 w4 = make_float4(acc[ii][q * 4], acc[ii][q * 4 + 1],
                                        acc[ii][q * 4 + 2], acc[ii][q * 4 + 3]);
                *(float4*)&redv[wv][l][ii * 8 + q * 4] = w4;
            }
    }
    __syncthreads();
    {
        const int ch = t & 127, g = ch >> 3, kk = ch & 7;
        const int ii = t >> 7;
        float sum = redv[0][g][ii * 8 + kk];
        #pragma unroll
        for (int w = 1; w < 8; ++w) sum += redv[w][g][ii * 8 + kk];
        const size_t ob = ((size_t)(b * N_ + i0 + ii)) * OUT_ + ch;
        out[ob] = fmaxf(sum * sinv[ii] + skipo[ob], 0.f);
    }
}

extern "C" void kernel_launch(void* const* d_in, const int* in_sizes, int n_in,
                              void* d_out, int out_size, void* d_ws, size_t ws_size,
                              hipStream_t stream) {
    const float* features   = (const float*)d_in[0];
    const float* e_features = (const float*)d_in[1];
    const float* g_features = (const float*)d_in[2];
    const float* adj        = (const float*)d_in[3];
    const float* Wm    = (const float*)d_in[4];
    const float* bm    = (const float*)d_in[5];
    const float* Wskip = (const float*)d_in[6];
    const float* bskip = (const float*)d_in[7];
    const float* W1    = (const float*)d_in[8];
    const float* b1    = (const float*)d_in[9];
    const float* W2    = (const float*)d_in[10];
    const float* b2    = (const float*)d_in[11];
    const float* We    = (const float*)d_in[12];
    const float* be    = (const float*)d_in[13];
    const float* Wg    = (const float*)d_in[14];
    const float* bg    = (const float*)d_in[15];
    const float* Wa    = (const float*)d_in[16];
    float* out = (float*)d_out;

    float* ws      = (float*)d_ws;
    float* values  = ws;                    // 262144
    float* skipo   = ws + 262144;           // 262144
    float* P1x     = ws + 524288;           // 131072
    float* p2      = ws + 655360;           // 131072
    float* pg      = ws + 786432;           // 128
    short* We_frag = (short*)(ws + 786560); // 2048 shorts

    prep_all<<<B_ * N_ / PR_ROWS + 2, 384, 0, stream>>>(
        features, g_features, Wm, bm, Wskip, bskip, W1, b1, W2, b2,
        We, be, Wg, bg, values, skipo, P1x, p2, pg, We_frag);
    gat_main<<<B_ * N_ / TI_, 512, 0, stream>>>(
        e_features, adj, We_frag, Wa, values, skipo, P1x, p2, pg, out);
}

// Round 2
// 290.313 us; speedup vs baseline: 1.1732x; 1.1732x over previous
//
#include <hip/hip_runtime.h>
#include <hip/hip_bf16.h>
#include <cstdint>

#define B_   2
#define N_   1024
#define DN_  128
#define DE_  16
#define DG_  128
#define MID_ 64
#define OUT_ 128
#define TI_  2
#define PR_ROWS 4

typedef short bf16x8 __attribute__((ext_vector_type(8)));
typedef float f32x4  __attribute__((ext_vector_type(4)));

__device__ inline short f2bf(float f) {
    union { float f; unsigned u; } v; v.f = f;
    unsigned r = v.u + 0x7FFFu + ((v.u >> 16) & 1u);   // RTNE
    return (short)(unsigned short)(r >> 16);
}

__device__ inline unsigned pk2(float lo, float hi) {
    union { __hip_bfloat162 h; unsigned u; } p;
    p.h = __float22bfloat162_rn(make_float2(lo, hi));  // v_cvt_pk_bf16_f32
    return p.u;
}

// ---------------------------------------------------------------------------
// Fused prep kernel (unchanged — ~25us, not the bottleneck).
//  blocks 0..511 : per-node projections, 4 rows/block.
//  block 512     : We -> MFMA B-fragment layout (bf16, K 16->32 zero-pad)
//  block 513     : pg[b] = g@Wg + bg
// ---------------------------------------------------------------------------
__global__ void __launch_bounds__(384) prep_all(
    const float* __restrict__ features, const float* __restrict__ g_features,
    const float* __restrict__ Wm, const float* __restrict__ bm,
    const float* __restrict__ Wskip, const float* __restrict__ bskip,
    const float* __restrict__ W1, const float* __restrict__ b1,
    const float* __restrict__ W2, const float* __restrict__ b2,
    const float* __restrict__ We, const float* __restrict__ be,
    const float* __restrict__ Wg, const float* __restrict__ bg,
    float* __restrict__ values, float* __restrict__ skipo,
    float* __restrict__ P1x, float* __restrict__ p2,
    float* __restrict__ pg, short* __restrict__ We_frag)
{
    const int t   = threadIdx.x;
    const int blk = blockIdx.x;

    if (blk == 512) {                       // --- We fragment prep ---
        for (int e = t; e < 4 * 64 * 8; e += 384) {
            const int c    = e >> 9;
            const int lane = (e >> 3) & 63;
            const int j    = e & 7;
            const int quad = lane >> 4, s = lane & 15;
            short v = 0;
            if (quad < 2) v = f2bf(We[(quad * 8 + j) * MID_ + c * 16 + s]);
            We_frag[e] = v;
        }
        return;
    }
    if (blk == 513) {                       // --- pg ---
        if (t < MID_) {
            float a0 = bg[t], a1 = bg[t];
            for (int k = 0; k < DG_; ++k) {
                const float w = Wg[k * MID_ + t];
                a0 += g_features[k] * w;
                a1 += g_features[DG_ + k] * w;
            }
            pg[t] = a0; pg[MID_ + t] = a1;
        }
        return;
    }

    // --- per-node projections ---
    const int r0 = blk * PR_ROWS;
    __shared__ float feat[PR_ROWS][DN_];
    for (int idx = t; idx < PR_ROWS * DN_; idx += 384)
        feat[idx >> 7][idx & 127] = features[(size_t)r0 * DN_ + idx];
    __syncthreads();

    const float* W; int c, stride; float base; float* outp; int ostride;
    if (t < 128) {
        W = Wm;    c = t;       stride = OUT_; base = bm[c];
        outp = values + (size_t)r0 * OUT_ + c; ostride = OUT_;
    } else if (t < 256) {
        W = Wskip; c = t - 128; stride = OUT_; base = bskip[c];
        outp = skipo + (size_t)r0 * OUT_ + c;  ostride = OUT_;
    } else if (t < 320) {
        W = W1;    c = t - 256; stride = MID_; base = b1[c] + be[c];
        outp = P1x + (size_t)r0 * MID_ + c;    ostride = MID_;
    } else {
        W = W2;    c = t - 320; stride = MID_; base = b2[c];
        outp = p2 + (size_t)r0 * MID_ + c;     ostride = MID_;
    }

    float acc[PR_ROWS] = {};
    for (int k = 0; k < DN_; ++k) {
        const float w = W[k * stride + c];
        #pragma unroll
        for (int q = 0; q < PR_ROWS; ++q) acc[q] += feat[q][k] * w;
    }
    #pragma unroll
    for (int q = 0; q < PR_ROWS; ++q) outp[q * ostride] = acc[q] + base;
}

// ---------------------------------------------------------------------------
// Main fused kernel: 1024 blocks x 256 threads (4 waves), TI=2 i-rows/block.
// R1 post-mortem: 512x512 + launch_bounds(512,4) forced VGPR to 64 -> ~450B/
// thread scratch spills (WRITE_SIZE 1MB->118MB), regressed. Occupancy must
// come from GRID, not from register-capped fat blocks: TI=2 doubles the grid
// (1024 blocks), per-thread state halves (eA/acc/p2i), natural VGPR ~90 under
// the 128 cap of (256,4) -> 4 blocks/CU = 16 waves/CU = 50%, zero spills.
//   Pass A: wave wv owns tiles {wv + 4*it}, it=0..15, ii=0..1.
//   Pass B: wave wv does row (wv&1), half (wv>>1); LDS combine of max/sum.
//   Pass C: 4 waves x 4 j-lanes x 64 k-steps; redv[4] planes.
// ---------------------------------------------------------------------------
__global__ void __launch_bounds__(256, 4) gat_main(
    const float* __restrict__ e_features, const float* __restrict__ adj,
    const short* __restrict__ We_frag, const float* __restrict__ Wa,
    const float* __restrict__ values, const float* __restrict__ skipo,
    const float* __restrict__ P1x, const float* __restrict__ p2,
    const float* __restrict__ pg, float* __restrict__ out)
{
    const int t    = threadIdx.x;
    const int wv   = t >> 6;                          // 0..3
    const int l    = t & 63;
    const int quad = l >> 4;
    const int s    = l & 15;
    const int r    = blockIdx.x;
    const int b    = (r >> 2) & 1;                    // XCD r%8 -> one batch
    const int i0   = (((r >> 3) << 2) | (r & 3)) * TI_;

    __shared__ float lgP[TI_][N_];
    __shared__ float redv[4][16][20];
    __shared__ float sinv[TI_];
    __shared__ float pmax[4];
    __shared__ float psum[4];

    // ---- block constants ----
    bf16x8 bfr[4];
    float  wa_r[4], p2i[TI_][4];
    #pragma unroll
    for (int c = 0; c < 4; ++c) {
        bfr[c]  = *(const bf16x8*)&We_frag[(c * 64 + l) * 8];
        wa_r[c] = Wa[c * 16 + s];
        const float pgc = pg[b * MID_ + c * 16 + s];
        #pragma unroll
        for (int ii = 0; ii < TI_; ++ii)
            p2i[ii][c] = p2[((size_t)(b * N_ + i0 + ii)) * MID_ + c * 16 + s] + pgc;
    }
    const size_t erow0 = (size_t)(b * N_ + i0) * N_;  // in e rows

    // ---- Pass A: software-pipelined logits (4 waves x 16 tiles) ----
    float4 eA[TI_][2];
    if (quad < 2) {
        #pragma unroll
        for (int ii = 0; ii < TI_; ++ii) {
            const float* ep = &e_features[(erow0 + (size_t)ii * N_ + wv * 16 + s) * DE_ + quad * 8];
            eA[ii][0] = *(const float4*)ep;
            eA[ii][1] = *(const float4*)(ep + 4);
        }
    }
    for (int it = 0; it < 16; ++it) {
        const int tile = wv + it * 4;
        const int j0   = tile * 16;

        // pack current tile's e into bf16 A-fragments
        unsigned af[TI_][4];
        #pragma unroll
        for (int ii = 0; ii < TI_; ++ii) {
            if (quad < 2) {
                af[ii][0] = pk2(eA[ii][0].x, eA[ii][0].y);
                af[ii][1] = pk2(eA[ii][0].z, eA[ii][0].w);
                af[ii][2] = pk2(eA[ii][1].x, eA[ii][1].y);
                af[ii][3] = pk2(eA[ii][1].z, eA[ii][1].w);
            } else {
                af[ii][0] = af[ii][1] = af[ii][2] = af[ii][3] = 0u;
            }
        }
        // prefetch next tile (fire-and-forget; consumed next iteration)
        if (it < 15) {
            const int jn = (tile + 4) * 16;
            if (quad < 2) {
                #pragma unroll
                for (int ii = 0; ii < TI_; ++ii) {
                    const float* ep = &e_features[(erow0 + (size_t)ii * N_ + jn + s) * DE_ + quad * 8];
                    eA[ii][0] = *(const float4*)ep;
                    eA[ii][1] = *(const float4*)(ep + 4);
                }
            }
        }
        // P1x bias tile (off MFMA critical path — consumed in epilogue)
        float base[4][4];
        {
            const float* pb = &P1x[((size_t)(b * N_) + j0 + quad * 4) * MID_ + s];
            #pragma unroll
            for (int c = 0; c < 4; ++c)
                #pragma unroll
                for (int rr = 0; rr < 4; ++rr)
                    base[c][rr] = pb[rr * MID_ + c * 16];
        }
        #pragma unroll
        for (int ii = 0; ii < TI_; ++ii) {
            union { unsigned u[4]; bf16x8 v; } a;
            a.u[0] = af[ii][0]; a.u[1] = af[ii][1];
            a.u[2] = af[ii][2]; a.u[3] = af[ii][3];
            f32x4 acc[4];
            #pragma unroll
            for (int c = 0; c < 4; ++c) {
                acc[c] = (f32x4){0.f, 0.f, 0.f, 0.f};
                acc[c] = __builtin_amdgcn_mfma_f32_16x16x32_bf16(a.v, bfr[c], acc[c], 0, 0, 0);
            }
            float tt[4];
            #pragma unroll
            for (int rr = 0; rr < 4; ++rr) {
                float x0 = acc[0][rr] + base[0][rr] + p2i[ii][0];
                float x1 = acc[1][rr] + base[1][rr] + p2i[ii][1];
                float x2 = acc[2][rr] + base[2][rr] + p2i[ii][2];
                float x3 = acc[3][rr] + base[3][rr] + p2i[ii][3];
                x0 = fmaxf(x0, 0.01f * x0);
                x1 = fmaxf(x1, 0.01f * x1);
                x2 = fmaxf(x2, 0.01f * x2);
                x3 = fmaxf(x3, 0.01f * x3);
                tt[rr] = x0 * wa_r[0] + x1 * wa_r[1] + x2 * wa_r[2] + x3 * wa_r[3];
            }
            #pragma unroll
            for (int o = 1; o < 16; o <<= 1) {
                tt[0] += __shfl_xor(tt[0], o);
                tt[1] += __shfl_xor(tt[1], o);
                tt[2] += __shfl_xor(tt[2], o);
                tt[3] += __shfl_xor(tt[3], o);
            }
            if (s < 4) lgP[ii][j0 + quad * 4 + s] = tt[s];
        }
    }
    __syncthreads();

    // ---- Pass B: masked softmax, wave wv owns row (wv&1), half (wv>>1) ----
    {
        const int rw = wv & 1, h = wv >> 1;
        const int c0 = h * 512 + l * 4;
        const size_t arb = (size_t)(b * N_ + i0 + rw) * N_;
        float4 lv[2], av[2];
        #pragma unroll
        for (int q = 0; q < 2; ++q) {
            lv[q] = *(const float4*)&lgP[rw][c0 + 256 * q];
            av[q] = *(const float4*)&adj[arb + c0 + 256 * q];
        }
        const float NEG = -3.4e38f;
        float m = NEG;
        #pragma unroll
        for (int q = 0; q < 2; ++q) {
            m = fmaxf(m, av[q].x > 0.f ? lv[q].x : NEG);
            m = fmaxf(m, av[q].y > 0.f ? lv[q].y : NEG);
            m = fmaxf(m, av[q].z > 0.f ? lv[q].z : NEG);
            m = fmaxf(m, av[q].w > 0.f ? lv[q].w : NEG);
        }
        #pragma unroll
        for (int o = 1; o < 64; o <<= 1) m = fmaxf(m, __shfl_xor(m, o));
        if (l == 0) pmax[wv] = m;
        __syncthreads();
        m = fmaxf(pmax[rw], pmax[2 + rw]);
        float sum = 0.f;
        #pragma unroll
        for (int q = 0; q < 2; ++q) {
            float4 e4;
            e4.x = av[q].x > 0.f ? __expf(lv[q].x - m) : 0.f;
            e4.y = av[q].y > 0.f ? __expf(lv[q].y - m) : 0.f;
            e4.z = av[q].z > 0.f ? __expf(lv[q].z - m) : 0.f;
            e4.w = av[q].w > 0.f ? __expf(lv[q].w - m) : 0.f;
            *(float4*)&lgP[rw][c0 + 256 * q] = e4;
            sum += (e4.x + e4.y) + (e4.z + e4.w);
        }
        #pragma unroll
        for (int o = 1; o < 64; o <<= 1) sum += __shfl_xor(sum, o);
        if (l == 0) psum[wv] = sum;
        __syncthreads();
        if (t < TI_) sinv[t] = 1.0f / (psum[t] + psum[t + 2]);
        // no extra barrier: lgP exp-writes are pre-psum-barrier; sinv is read
        // only after the redv barrier below.
    }

    // ---- Pass C: (exp @ values) shared across the 2 i-rows ----
    const int cg = l & 15, jp = l >> 4, ch0 = cg * 8;
    float acc[TI_][8] = {};
    const float* vb = values + (size_t)b * N_ * OUT_ + ch0;
    for (int k = 0; k < 64; ++k) {
        const int j = wv * 4 + jp + k * 16;
        float cw[TI_];
        #pragma unroll
        for (int ii = 0; ii < TI_; ++ii) cw[ii] = lgP[ii][j];
        const float* vp = vb + (size_t)j * OUT_;
        const float4 v0 = *(const float4*)vp;
        const float4 v1 = *(const float4*)(vp + 4);
        const float vv[8] = {v0.x, v0.y, v0.z, v0.w, v1.x, v1.y, v1.z, v1.w};
        #pragma unroll
        for (int ii = 0; ii < TI_; ++ii)
            #pragma unroll
            for (int kk = 0; kk < 8; ++kk)
                acc[ii][kk] += cw[ii] * vv[kk];
    }
    #pragma unroll
    for (int ii = 0; ii < TI_; ++ii)
        #pragma unroll
        for (int kk = 0; kk < 8; ++kk) {
            acc[ii][kk] += __shfl_xor(acc[ii][kk], 16);
            acc[ii][kk] += __shfl_xor(acc[ii][kk], 32);
        }
    if (l < 16) {
        #pragma unroll
        for (int ii = 0; ii < TI_; ++ii)
            #pragma unroll
            for (int q = 0; q < 2; ++q) {
                float4 w4 = make_float4(acc[ii][q * 4], acc[ii][q * 4 + 1],
                                        acc[ii][q * 4 + 2], acc[ii][q * 4 + 3]);
                *(float4*)&redv[wv][l][ii * 8 + q * 4] = w4;
            }
    }
    __syncthreads();
    {
        const int ch = t & 127, g = ch >> 3, kk = ch & 7;
        const int ii = t >> 7;                        // 0..1
        float sum = redv[0][g][ii * 8 + kk];
        #pragma unroll
        for (int w = 1; w < 4; ++w) sum += redv[w][g][ii * 8 + kk];
        const size_t ob = ((size_t)(b * N_ + i0 + ii)) * OUT_ + ch;
        out[ob] = fmaxf(sum * sinv[ii] + skipo[ob], 0.f);
    }
}

extern "C" void kernel_launch(void* const* d_in, const int* in_sizes, int n_in,
                              void* d_out, int out_size, void* d_ws, size_t ws_size,
                              hipStream_t stream) {
    const float* features   = (const float*)d_in[0];
    const float* e_features = (const float*)d_in[1];
    const float* g_features = (const float*)d_in[2];
    const float* adj        = (const float*)d_in[3];
    const float* Wm    = (const float*)d_in[4];
    const float* bm    = (const float*)d_in[5];
    const float* Wskip = (const float*)d_in[6];
    const float* bskip = (const float*)d_in[7];
    const float* W1    = (const float*)d_in[8];
    const float* b1    = (const float*)d_in[9];
    const float* W2    = (const float*)d_in[10];
    const float* b2    = (const float*)d_in[11];
    const float* We    = (const float*)d_in[12];
    const float* be    = (const float*)d_in[13];
    const float* Wg    = (const float*)d_in[14];
    const float* bg    = (const float*)d_in[15];
    const float* Wa    = (const float*)d_in[16];
    float* out = (float*)d_out;

    float* ws      = (float*)d_ws;
    float* values  = ws;                    // 262144
    float* skipo   = ws + 262144;           // 262144
    float* P1x     = ws + 524288;           // 131072
    float* p2      = ws + 655360;           // 131072
    float* pg      = ws + 786432;           // 128
    short* We_frag = (short*)(ws + 786560); // 2048 shorts

    prep_all<<<B_ * N_ / PR_ROWS + 2, 384, 0, stream>>>(
        features, g_features, Wm, bm, Wskip, bskip, W1, b1, W2, b2,
        We, be, Wg, bg, values, skipo, P1x, p2, pg, We_frag);
    gat_main<<<B_ * N_ / TI_, 256, 0, stream>>>(
        e_features, adj, We_frag, Wa, values, skipo, P1x, p2, pg, out);
}